// Round 8
// baseline (239.149 us; speedup 1.0000x reference)
//
#include <hip/hip_runtime.h>
#include <hip/hip_bf16.h>

// CrossAttentionFusion: B=4, C=Cs=256, CI=128, H=W=64 -> N=M=4096
// R14 = QK/softmax dedup via 4-way KEY split (no sharing, no barriers):
//  - R13 post-mortem: counted-vmcnt only -7us; MfmaUtil+VALUBusy ~75% =>
//    issue/work-limited. 25% of MFMA + 50% of exp is chh-pair duplication.
//  - R14: wave w owns keys [t*128 + w*32, +32) and the FULL 256-ch PV for
//    them. QK+softmax computed once per key (was twice). P stays in-wave
//    (R10's LDS-publish failure avoided). K/V bytes wave-private -> main
//    loop has ZERO barriers and reads K/V direct from global (L2-resident,
//    b=(i&7)>>1 XCD-pair map). R9's register starvation avoided: 4 waves
//    (not 12), launch_bounds(256,2) -> ~256 regs/wave for Oacc[8]=128 AGPR.
//  - V loaded in 2 batches: cg0-3 issued under softmax, cg4-7 under PV-A.
//  - Epilogue: O merged 4-way in LDS (w0 store, w1-3 ds_add_f32), l via
//    redu[4]; 2 barriers total. setprio(1) around PV MFMA cluster (T5).
//  - prep/proj unchanged (R11 1024-grid proj).
//
// qk-frag (Q B-op / K A-op), per 32-row group g:
//   addr = g*4096 + (ch>>4)*512 + ((ch>>3)&1)*256 + row*8 + (ch&7)
//   (K rows permuted: row = l32^12 if (l32>>2)&3 in {1,2} -> shuffle-free PV)
// V-frag (PV A-op), per 32-key group g: addr = g*8192 + (ch>>5)*1024
//   + ((key>>4)&1)*512 + ((key>>3)&1)*256 + (ch&31)*8 + (key&7)

typedef __bf16  bf16x8  __attribute__((ext_vector_type(8)));
typedef float   f32x16  __attribute__((ext_vector_type(16)));

#define LOG2E 1.4426950408889634f

union BF8 { __hip_bfloat162 h[4]; bf16x8 v; };
union U4  { unsigned u[4]; bf16x8 v; };

__device__ inline bf16x8 pack8(const float f[8]) {
  BF8 u;
#pragma unroll
  for (int i = 0; i < 4; i++)
    u.h[i] = __float22bfloat162_rn(float2{f[2 * i], f[2 * i + 1]});
  return u.v;
}

// ---------------------------------------------------------------------------
// prep: blocks [0,512): x/z -> X-frag bf16 (LDS transpose, float4 loads);
//       blocks [512,516): W -> W-frag bf16.  (unchanged from R8)
// ---------------------------------------------------------------------------
__global__ __launch_bounds__(256) void prep_kernel(
    const float* __restrict__ x, const float* __restrict__ z,
    const float* __restrict__ Wq, const float* __restrict__ Wk,
    const float* __restrict__ Wv,
    __hip_bfloat16* __restrict__ xf, __hip_bfloat16* __restrict__ zf,
    __hip_bfloat16* __restrict__ wfr)
{
  __shared__ float lds[256 * 68];   // pitch 68: 16B-aligned rows, conflict-free
  const int bi = blockIdx.x;
  const int tid = threadIdx.x;
  if (bi < 512) {
    const int sel = bi >> 8;
    const int b   = (bi >> 6) & 3;
    const int pc  = bi & 63;
    const float* in = sel ? z : x;
    __hip_bfloat16* outp = sel ? zf : xf;
    const size_t ib = (size_t)b * 256 * 4096 + pc * 64;
    const int pix4 = (tid & 15) * 4;
#pragma unroll
    for (int it = 0; it < 16; it++) {
      int ch = it * 16 + (tid >> 4);
      float4 v4 = *(const float4*)&in[ib + (size_t)ch * 4096 + pix4];
      *(float4*)&lds[ch * 68 + pix4] = v4;
    }
    __syncthreads();
    const size_t ob = ((size_t)(b * 128 + pc * 2)) * 8192;
#pragma unroll
    for (int i = 0; i < 8; i++) {
      int c = i * 256 + tid;
      int grp = c >> 10, cs = (c >> 6) & 15, rem = c & 63;
      int hf = rem >> 5, l32 = rem & 31;
      float f[8];
      int chb = cs * 16 + hf * 8;
#pragma unroll
      for (int j = 0; j < 8; j++)
        f[j] = lds[(chb + j) * 68 + grp * 32 + l32];
      *(bf16x8*)(outp + ob + grp * 8192 + cs * 512 + hf * 256 + l32 * 8) =
          pack8(f);
    }
  } else {
    const int base = (bi - 512) * 4096;
#pragma unroll
    for (int i = 0; i < 16; i++) {
      int c = base + i * 256 + tid;
      const float* Ws; __hip_bfloat16* dst; int rc;
      if (c < 4096)      { Ws = Wq; dst = wfr;          rc = c; }
      else if (c < 8192) { Ws = Wk; dst = wfr + 32768;  rc = c - 4096; }
      else               { Ws = Wv; dst = wfr + 65536;  rc = c - 8192; }
      int ot = rc >> 10, cs = (rc >> 6) & 15, rem = rc & 63;
      int hf = rem >> 5, l32 = rem & 31;
      const float* src = Ws + (ot * 32 + l32) * 256 + cs * 16 + hf * 8;
      float f[8];
#pragma unroll
      for (int j = 0; j < 8; j++) f[j] = src[j];
      *(bf16x8*)(dst + ot * 8192 + cs * 512 + hf * 256 + l32 * 8) = pack8(f);
    }
  }
}

// ---------------------------------------------------------------------------
// proj: LDS-free MFMA GEMM, one O0/O1 pixel-group pair per block (ILP 2),
// direct stores. Grid 1024: [0,256) q, [256,512) k, [512,1024) v.  (R11)
// ---------------------------------------------------------------------------
__global__ __launch_bounds__(256, 3) void proj_mfma(
    const __hip_bfloat16* __restrict__ xf, const __hip_bfloat16* __restrict__ zf,
    const __hip_bfloat16* __restrict__ wfr,
    const float* __restrict__ bq, const float* __restrict__ bk,
    const float* __restrict__ bv,
    __hip_bfloat16* __restrict__ qp, __hip_bfloat16* __restrict__ kp,
    __hip_bfloat16* __restrict__ vp)
{
  const int bi = blockIdx.x;
  int mode, b, pg0, h = 0;
  if (bi < 512) { mode = bi >> 8; b = (bi >> 6) & 3; pg0 = (bi & 63) * 2; }
  else { int j = bi - 512; mode = 2; b = j >> 7; pg0 = ((j >> 1) & 63) * 2; h = j & 1; }
  const int tid = threadIdx.x, w = tid >> 6, lane = tid & 63,
            l32 = lane & 31, half = lane >> 5;

  const __hip_bfloat16* X = (mode == 0) ? xf : zf;
  const int wtile = (mode == 2 ? h * 4 : 0) + w;
  const int wbase = (mode == 0) ? 0 : (mode == 1) ? 32768 : 65536;
  const __hip_bfloat16* wp = wfr + wbase + wtile * 8192 + lane * 8;
  bf16x8 wfg[16];
#pragma unroll
  for (int cs = 0; cs < 16; cs++) wfg[cs] = *(const bf16x8*)(wp + cs * 512);

  const float* bias = (mode == 0) ? bq : (mode == 1) ? bk : bv;
  const int ochb = (mode == 2 ? h * 128 : 0) + w * 32;
  float bb[16];
#pragma unroll
  for (int r = 0; r < 16; r++)
    bb[r] = bias[ochb + (r & 3) + 8 * (r >> 2) + 4 * half];

  const int t4 = (l32 >> 2) & 3;
  const int kperm = (t4 == 1 || t4 == 2) ? (l32 ^ 12) : l32;

  const __hip_bfloat16* xb0 = X + ((size_t)(b * 128 + pg0)) * 8192 + lane * 8;
  const __hip_bfloat16* xb1 = xb0 + 8192;
  f32x16 O0 = {}, O1 = {};
#pragma unroll
  for (int cs = 0; cs < 16; cs++) {
    bf16x8 xr0 = *(const bf16x8*)(xb0 + cs * 512);
    bf16x8 xr1 = *(const bf16x8*)(xb1 + cs * 512);
    O0 = __builtin_amdgcn_mfma_f32_32x32x16_bf16(wfg[cs], xr0, O0, 0, 0, 0);
    O1 = __builtin_amdgcn_mfma_f32_32x32x16_bf16(wfg[cs], xr1, O1, 0, 0, 0);
  }
#pragma unroll
  for (int p = 0; p < 2; p++) {
    const f32x16& O = p ? O1 : O0;
    const int pg = pg0 + p;
    if (mode == 0) {
      __hip_bfloat16* qb = qp + ((size_t)(b * 128 + pg)) * 4096;
#pragma unroll
      for (int r = 0; r < 16; r++) {
        int oc = ochb + (r & 3) + 8 * (r >> 2) + 4 * half;
        qb[(oc >> 4) * 512 + ((oc >> 3) & 1) * 256 + l32 * 8 + (oc & 7)] =
            __float2bfloat16((O[r] + bb[r]) * LOG2E);
      }
    } else if (mode == 1) {
      __hip_bfloat16* kb = kp + ((size_t)(b * 128 + pg)) * 4096;
#pragma unroll
      for (int r = 0; r < 16; r++) {
        int oc = ochb + (r & 3) + 8 * (r >> 2) + 4 * half;
        kb[(oc >> 4) * 512 + ((oc >> 3) & 1) * 256 + kperm * 8 + (oc & 7)] =
            __float2bfloat16(O[r] + bb[r]);
      }
    } else {
      __hip_bfloat16* vb = vp + ((size_t)(b * 128 + pg)) * 8192
          + (h * 4 + w) * 1024 + (l32 >> 4) * 512 + ((l32 >> 3) & 1) * 256
          + (l32 & 7);
#pragma unroll
      for (int r = 0; r < 16; r++) {
        int rr = (r & 3) + 8 * (r >> 2) + 4 * half;
        vb[rr * 8] = __float2bfloat16(O[r] + bb[r]);
      }
    }
  }
}

// ---------------------------------------------------------------------------
// attn R14: grid 512 = (b, 32q), 4 waves; wave w owns key-slice w of each
// 128-key tile (32 tiles) and the FULL 256-ch PV (Oacc[8] = 128 AGPR).
// No duplicated QK/exp; no cross-wave sharing; ZERO main-loop barriers;
// K/V direct from global. Epilogue: 4-way LDS merge (store + ds_add_f32).
// ---------------------------------------------------------------------------
struct AttnSmem {
  float ost[256][33];          // merge buffer [ch][q], pad 33
  float redu[4][32];
  float rinv[32];
};

__global__ __launch_bounds__(256, 2) void attn_kernel(
    const __hip_bfloat16* __restrict__ qv, const __hip_bfloat16* __restrict__ kv,
    const __hip_bfloat16* __restrict__ vv,
    const float* __restrict__ x_main, const float* __restrict__ gammap,
    float* __restrict__ out)
{
  __shared__ AttnSmem sm;
  const int i  = blockIdx.x;           // 512 blocks
  const int b  = (i & 7) >> 1;         // XCD-pair -> batch (K+V L2-resident)
  const int qt = ((i >> 3) << 1) | (i & 1);
  const int n0 = qt * 32;
  const int tid  = threadIdx.x;
  const int w    = tid >> 6, lane = tid & 63, l32 = lane & 31, hb = lane >> 5;
  const int t0   = qt & 31;            // stagger: de-correlate block streams

  // Q B-fragments (per-wave copy in regs; 8KB per block from L2)
  bf16x8 qf[8];
  {
    const __hip_bfloat16* qb = qv + ((size_t)(b * 128 + qt)) * 4096 + lane * 8;
#pragma unroll
    for (int cs = 0; cs < 8; cs++) qf[cs] = *(const bf16x8*)(qb + cs * 512);
  }

  const __hip_bfloat16* kg = kv + (size_t)(b * 128) * 4096;
  const __hip_bfloat16* vg = vv + (size_t)(b * 128) * 8192;

  f32x16 Oacc[8];   // O^T: FULL 256 ch x 32 q, partial over this wave's keys
#pragma unroll
  for (int cg = 0; cg < 8; cg++)
#pragma unroll
    for (int r = 0; r < 16; r++) Oacc[cg][r] = 0.f;

  float l_lane = 0.f;

  // ---- main loop: 32 tiles x 128 keys; wave owns 32-key group g4 ----
#pragma unroll 1
  for (int lt = 0; lt < 32; ++lt) {
    const int g4 = ((lt + t0) & 31) * 4 + w;       // 32-key group in [0,128)
    const __hip_bfloat16* kb = kg + (size_t)g4 * 4096 + lane * 8;
    const __hip_bfloat16* vb = vg + (size_t)g4 * 8192 + lane * 8;

    // K frags for this wave's 32 keys
    bf16x8 kf[8];
#pragma unroll
    for (int cs = 0; cs < 8; cs++) kf[cs] = *(const bf16x8*)(kb + cs * 512);

    // S^T = K Q (once per key — no chh duplication)
    f32x16 S = {};
#pragma unroll
    for (int cs = 0; cs < 8; cs++)
      S = __builtin_amdgcn_mfma_f32_32x32x16_bf16(kf[cs], qf[cs], S, 0, 0, 0);

    // V batch A (ch-groups 0..3) — latency hides under softmax
    bf16x8 Va[8];
#pragma unroll
    for (int cg = 0; cg < 4; cg++) {
      Va[2 * cg]     = *(const bf16x8*)(vb + cg * 1024);
      Va[2 * cg + 1] = *(const bf16x8*)(vb + cg * 1024 + 512);
    }

    // P = exp2(S - 64), pack bf16 (shuffle-free via K perm)
    unsigned p2[8];
    float lsub = 0.f;
#pragma unroll
    for (int i2 = 0; i2 < 8; i2++) {
      float a = exp2f(S[2 * i2]     - 64.0f);
      float c = exp2f(S[2 * i2 + 1] - 64.0f);
      lsub += a + c;
      union { __hip_bfloat162 h; unsigned u; } cv;
      cv.h = __float22bfloat162_rn(float2{a, c});
      p2[i2] = cv.u;
    }
    l_lane += lsub;
    U4 f0, f1;
    f0.u[0] = p2[0]; f0.u[1] = p2[1]; f0.u[2] = p2[2]; f0.u[3] = p2[3];
    f1.u[0] = p2[4]; f1.u[1] = p2[5]; f1.u[2] = p2[6]; f1.u[3] = p2[7];
    const bf16x8 pf0 = f0.v, pf1 = f1.v;

    // V batch B (ch-groups 4..7) — latency hides under PV-A
    bf16x8 Vb2[8];
#pragma unroll
    for (int cg = 0; cg < 4; cg++) {
      Vb2[2 * cg]     = *(const bf16x8*)(vb + 4096 + cg * 1024);
      Vb2[2 * cg + 1] = *(const bf16x8*)(vb + 4096 + cg * 1024 + 512);
    }

    // PV: full 256 ch (8 independent accumulators)
    __builtin_amdgcn_s_setprio(1);
#pragma unroll
    for (int cg = 0; cg < 4; cg++) {
      Oacc[cg] = __builtin_amdgcn_mfma_f32_32x32x16_bf16(Va[2 * cg],     pf0, Oacc[cg], 0, 0, 0);
      Oacc[cg] = __builtin_amdgcn_mfma_f32_32x32x16_bf16(Va[2 * cg + 1], pf1, Oacc[cg], 0, 0, 0);
    }
#pragma unroll
    for (int cg = 0; cg < 4; cg++) {
      Oacc[4 + cg] = __builtin_amdgcn_mfma_f32_32x32x16_bf16(Vb2[2 * cg],     pf0, Oacc[4 + cg], 0, 0, 0);
      Oacc[4 + cg] = __builtin_amdgcn_mfma_f32_32x32x16_bf16(Vb2[2 * cg + 1], pf1, Oacc[4 + cg], 0, 0, 0);
    }
    __builtin_amdgcn_s_setprio(0);
  }

  // ---- epilogue: l publish + 4-way O merge in LDS + writeout ----
  float lfull = l_lane + __shfl_xor(l_lane, 32);
  if (lane < 32) sm.redu[w][l32] = lfull;
  if (w == 0) {
#pragma unroll
    for (int cg = 0; cg < 8; cg++) {
#pragma unroll
      for (int r = 0; r < 16; r++) {
        int ch = cg * 32 + (r & 3) + 8 * (r >> 2) + 4 * hb;
        sm.ost[ch][l32] = Oacc[cg][r];
      }
    }
  }
  __syncthreads();                 // redu + w0's ost published
  if (w != 0) {
#pragma unroll
    for (int cg = 0; cg < 8; cg++) {
#pragma unroll
      for (int r = 0; r < 16; r++) {
        int ch = cg * 32 + (r & 3) + 8 * (r >> 2) + 4 * hb;
        atomicAdd(&sm.ost[ch][l32], Oacc[cg][r]);   // ds_add_f32
      }
    }
  }
  if (tid < 32)
    sm.rinv[tid] = 1.0f / (sm.redu[0][tid] + sm.redu[1][tid] +
                           sm.redu[2][tid] + sm.redu[3][tid]);
  __syncthreads();

  const float gmm = gammap[0];
  const int pix = tid & 31;
  const float ri = sm.rinv[pix];
#pragma unroll
  for (int j = 0; j < 32; ++j) {
    int ch = (tid >> 5) * 32 + j;
    size_t g = ((size_t)(b * 256 + ch)) * 4096 + n0 + pix;
    out[g] = gmm * sm.ost[ch][pix] * ri + x_main[g];
  }
}

// ---------------------------------------------------------------------------
extern "C" void kernel_launch(void* const* d_in, const int* in_sizes, int n_in,
                              void* d_out, int out_size, void* d_ws, size_t ws_size,
                              hipStream_t stream) {
  (void)in_sizes; (void)n_in; (void)out_size; (void)ws_size;
  const float* x  = (const float*)d_in[0];
  const float* z  = (const float*)d_in[1];
  const float* Wq = (const float*)d_in[2];
  const float* bq = (const float*)d_in[3];
  const float* Wk = (const float*)d_in[4];
  const float* bk = (const float*)d_in[5];
  const float* Wv = (const float*)d_in[6];
  const float* bv = (const float*)d_in[7];
  const float* gm = (const float*)d_in[8];
  float* out = (float*)d_out;

  char* ws = (char*)d_ws;
  const size_t MB = 1024 * 1024;
  __hip_bfloat16* qp  = (__hip_bfloat16*)(ws);             // 4 MiB
  __hip_bfloat16* kp  = (__hip_bfloat16*)(ws + 4 * MB);    // 4 MiB
  __hip_bfloat16* vp  = (__hip_bfloat16*)(ws + 8 * MB);    // 8 MiB
  __hip_bfloat16* xfp = (__hip_bfloat16*)(ws + 16 * MB);   // 8 MiB
  __hip_bfloat16* zfp = (__hip_bfloat16*)(ws + 24 * MB);   // 8 MiB
  __hip_bfloat16* wfp = (__hip_bfloat16*)(ws + 32 * MB);   // 256 KiB

  prep_kernel<<<516, 256, 0, stream>>>(x, z, Wq, Wk, Wv, xfp, zfp, wfp);
  proj_mfma  <<<1024, 256, 0, stream>>>(xfp, zfp, wfp, bq, bk, bv, qp, kp, vp);
  attn_kernel<<<512, 256, 0, stream>>>(qp, kp, vp, x, gm, out);
}

// Round 9
// 202.642 us; speedup vs baseline: 1.1802x; 1.1802x over previous
//
#include <hip/hip_runtime.h>
#include <hip/hip_bf16.h>

// CrossAttentionFusion: B=4, C=Cs=256, CI=128, H=W=64 -> N=M=4096
// R15 = fuse prep+proj (the non-attn ~100us is the target):
//  - Ledger R0..R14: total - attn ~= 96-108us for EVERY attn variant, while
//    prep+proj roofline is ~18us. The xf/zf HBM round-trip (write 16.7MB,
//    re-read ~25MB) + kernel-boundary serialization is pure overhead.
//  - projfused (512 thr, 512 blocks, 67.6KB LDS -> 2 blocks/CU):
//    per block (b, 64 pix): stage x/z tile via LDS in two 128-ch halves
//    (f32 [128][68]), pack to frag-layout bf16 LDS (prep's exact transform),
//    then MFMA direct from LDS; scatter stores verbatim from proj.
//    q-blocks: 8 jobs (4 oc-tiles x 2 pg) over 8 waves. kv-blocks: z read
//    once -> K (4 tiles) + V (8 tiles) x 2 pg = 24 jobs, 3/wave, same-pg
//    jobs share B-frags in regs (wfg reloaded per job from wfr, L2-hot).
//  - wprep: W -> frag bf16, 16 blocks (prep's else-branch spread 4x).
//  - attn: R13 byte-identical (measured 106.5us best; counted-vmcnt kbuf[3]).
//
// qk-frag (Q B-op / K A-op), per 32-row group g:
//   addr = g*4096 + (ch>>4)*512 + ((ch>>3)&1)*256 + row*8 + (ch&7)
//   (K rows permuted: row = l32^12 if (l32>>2)&3 in {1,2} -> shuffle-free PV)
// V-frag (PV A-op), per 32-key group g: addr = g*8192 + (ch>>5)*1024
//   + ((key>>4)&1)*512 + ((key>>3)&1)*256 + (ch&31)*8 + (key&7)

typedef __bf16  bf16x8  __attribute__((ext_vector_type(8)));
typedef float   f32x16  __attribute__((ext_vector_type(16)));

#define LOG2E 1.4426950408889634f

union BF8 { __hip_bfloat162 h[4]; bf16x8 v; };
union U4  { unsigned u[4]; bf16x8 v; };

__device__ inline bf16x8 pack8(const float f[8]) {
  BF8 u;
#pragma unroll
  for (int i = 0; i < 4; i++)
    u.h[i] = __float22bfloat162_rn(float2{f[2 * i], f[2 * i + 1]});
  return u.v;
}

__device__ inline void dma16(const void* g, void* l) {
  __builtin_amdgcn_global_load_lds(
      (const __attribute__((address_space(1))) unsigned int*)g,
      (__attribute__((address_space(3))) unsigned int*)l, 16, 0, 0);
}

// ---------------------------------------------------------------------------
// wprep: W -> W-frag bf16 (prep's else-branch, spread over 16 blocks).
// ---------------------------------------------------------------------------
__global__ __launch_bounds__(256) void wprep_kernel(
    const float* __restrict__ Wq, const float* __restrict__ Wk,
    const float* __restrict__ Wv, __hip_bfloat16* __restrict__ wfr)
{
  const int base = blockIdx.x * 1024;
  const int tid = threadIdx.x;
#pragma unroll
  for (int i = 0; i < 4; i++) {
    int c = base + i * 256 + tid;          // [0, 16384)
    const float* Ws; __hip_bfloat16* dst; int rc;
    if (c < 4096)      { Ws = Wq; dst = wfr;          rc = c; }
    else if (c < 8192) { Ws = Wk; dst = wfr + 32768;  rc = c - 4096; }
    else               { Ws = Wv; dst = wfr + 65536;  rc = c - 8192; }
    int ot = rc >> 10, cs = (rc >> 6) & 15, rem = rc & 63;
    int hf = rem >> 5, l32 = rem & 31;
    const float* src = Ws + (ot * 32 + l32) * 256 + cs * 16 + hf * 8;
    float f[8];
#pragma unroll
    for (int j = 0; j < 8; j++) f[j] = src[j];
    *(bf16x8*)(dst + ot * 8192 + cs * 512 + hf * 256 + l32 * 8) = pack8(f);
  }
}

// ---------------------------------------------------------------------------
// projfused: stage input tile via LDS (two 128-ch halves), pack to frag-LDS,
// MFMA from LDS, direct scatter stores. Grid 512: [0,256) q(x), [256,512) kv(z).
// 512 threads = 8 waves; 67.6KB LDS -> 2 blocks/CU.
// ---------------------------------------------------------------------------
struct PFSmem {
  float stg[128 * 68];               // 34,816 B (pitch 68, conflict-free)
  alignas(16) __hip_bfloat16 frag[16384];  // 32,768 B, frag layout [pg][cs][hf][l32][8]
};

__global__ __launch_bounds__(512, 2) void projfused(
    const float* __restrict__ x, const float* __restrict__ z,
    const __hip_bfloat16* __restrict__ wfr,
    const float* __restrict__ bq, const float* __restrict__ bk,
    const float* __restrict__ bv,
    __hip_bfloat16* __restrict__ qp, __hip_bfloat16* __restrict__ kp,
    __hip_bfloat16* __restrict__ vp)
{
  __shared__ PFSmem sm;
  const int bi = blockIdx.x;
  const bool qmode = bi < 256;
  const int j2 = qmode ? bi : bi - 256;
  const int b = j2 >> 6, pc = j2 & 63;
  const float* in = qmode ? x : z;
  const size_t ib = (size_t)b * 256 * 4096 + pc * 64;

  const int tid = threadIdx.x, w = tid >> 6, lane = tid & 63,
            l32 = lane & 31, half = lane >> 5;
  const int pix4 = (tid & 15) * 4;

  // ---- stage/pack half 0 (ch 0..127 -> cs 0..7) ----
#pragma unroll
  for (int it = 0; it < 4; it++) {
    int ch = it * 32 + (tid >> 4);
    float4 v4 = *(const float4*)&in[ib + (size_t)ch * 4096 + pix4];
    *(float4*)&sm.stg[ch * 68 + pix4] = v4;
  }
  __syncthreads();
#pragma unroll
  for (int i = 0; i < 2; i++) {
    int c = i * 512 + tid;               // [0,1024)
    int grp = c >> 9, csl = (c >> 6) & 7, rem = c & 63;
    int hf = rem >> 5, lr = rem & 31;
    int chb = csl * 16 + hf * 8;
    float f[8];
#pragma unroll
    for (int j = 0; j < 8; j++) f[j] = sm.stg[(chb + j) * 68 + grp * 32 + lr];
    *(bf16x8*)(sm.frag + grp * 8192 + csl * 512 + hf * 256 + lr * 8) = pack8(f);
  }
  __syncthreads();                       // pack0 done reading stg

  // ---- stage/pack half 1 (ch 128..255 -> cs 8..15) ----
#pragma unroll
  for (int it = 0; it < 4; it++) {
    int ch = it * 32 + (tid >> 4);
    float4 v4 = *(const float4*)&in[ib + (size_t)(128 + ch) * 4096 + pix4];
    *(float4*)&sm.stg[ch * 68 + pix4] = v4;
  }
  __syncthreads();
#pragma unroll
  for (int i = 0; i < 2; i++) {
    int c = i * 512 + tid;
    int grp = c >> 9, csl = (c >> 6) & 7, rem = c & 63;
    int hf = rem >> 5, lr = rem & 31;
    int chb = csl * 16 + hf * 8;
    float f[8];
#pragma unroll
    for (int j = 0; j < 8; j++) f[j] = sm.stg[(chb + j) * 68 + grp * 32 + lr];
    *(bf16x8*)(sm.frag + grp * 8192 + (csl + 8) * 512 + hf * 256 + lr * 8) =
        pack8(f);
  }
  __syncthreads();                       // frag complete

  const int t4 = (l32 >> 2) & 3;
  const int kperm = (t4 == 1 || t4 == 2) ? (l32 ^ 12) : l32;

  if (qmode) {
    // 8 jobs: wave w -> (ot = w>>1, pg = w&1)
    const int ot = w >> 1, pg = w & 1;
    // B-frags from LDS (shared by ot-pairs; conflict-free lane*16B)
    bf16x8 bfr[16];
#pragma unroll
    for (int cs = 0; cs < 16; cs++)
      bfr[cs] = *(const bf16x8*)(sm.frag + pg * 8192 + cs * 512 + lane * 8);
    const __hip_bfloat16* wp = wfr + ot * 8192 + lane * 8;
    bf16x8 wfg[16];
#pragma unroll
    for (int cs = 0; cs < 16; cs++) wfg[cs] = *(const bf16x8*)(wp + cs * 512);
    float bb[16];
#pragma unroll
    for (int r = 0; r < 16; r++)
      bb[r] = bq[ot * 32 + (r & 3) + 8 * (r >> 2) + 4 * half];
    f32x16 O = {};
#pragma unroll
    for (int cs = 0; cs < 16; cs++)
      O = __builtin_amdgcn_mfma_f32_32x32x16_bf16(wfg[cs], bfr[cs], O, 0, 0, 0);
    __hip_bfloat16* qb = qp + ((size_t)(b * 128 + pc * 2 + pg)) * 4096;
#pragma unroll
    for (int r = 0; r < 16; r++) {
      int oc = ot * 32 + (r & 3) + 8 * (r >> 2) + 4 * half;
      qb[(oc >> 4) * 512 + ((oc >> 3) & 1) * 256 + l32 * 8 + (oc & 7)] =
          __float2bfloat16((O[r] + bb[r]) * LOG2E);
    }
  } else {
    // 24 jobs: wave w -> j in {w, w+8, w+16}; pg = w&1 constant per wave.
    const int pg = w & 1;
    bf16x8 bfr[16];
#pragma unroll
    for (int cs = 0; cs < 16; cs++)
      bfr[cs] = *(const bf16x8*)(sm.frag + pg * 8192 + cs * 512 + lane * 8);
    const size_t pgg = (size_t)(b * 128 + pc * 2 + pg);
#pragma unroll
    for (int jj = 0; jj < 3; jj++) {
      const int t = (w + jj * 8) >> 1;         // [0,12): t<4 K, else V tile t-4
      const bool isK = (t < 4);
      const __hip_bfloat16* wp = wfr + (isK ? 32768 + t * 8192
                                            : 65536 + (t - 4) * 8192) + lane * 8;
      bf16x8 wfg[16];
#pragma unroll
      for (int cs = 0; cs < 16; cs++) wfg[cs] = *(const bf16x8*)(wp + cs * 512);
      const float* bias = isK ? bk : bv;
      const int ocb = (isK ? t : t - 4) * 32;
      float bb[16];
#pragma unroll
      for (int r = 0; r < 16; r++)
        bb[r] = bias[ocb + (r & 3) + 8 * (r >> 2) + 4 * half];
      f32x16 O = {};
#pragma unroll
      for (int cs = 0; cs < 16; cs++)
        O = __builtin_amdgcn_mfma_f32_32x32x16_bf16(wfg[cs], bfr[cs], O, 0, 0, 0);
      if (isK) {
        __hip_bfloat16* kb = kp + pgg * 4096;
#pragma unroll
        for (int r = 0; r < 16; r++) {
          int oc = t * 32 + (r & 3) + 8 * (r >> 2) + 4 * half;
          kb[(oc >> 4) * 512 + ((oc >> 3) & 1) * 256 + kperm * 8 + (oc & 7)] =
              __float2bfloat16(O[r] + bb[r]);
        }
      } else {
        __hip_bfloat16* vb = vp + pgg * 8192 + (t - 4) * 1024
            + (l32 >> 4) * 512 + ((l32 >> 3) & 1) * 256 + (l32 & 7);
#pragma unroll
        for (int r = 0; r < 16; r++) {
          int rr = (r & 3) + 8 * (r >> 2) + 4 * half;
          vb[rr * 8] = __float2bfloat16(O[r] + bb[r]);
        }
      }
    }
  }
}

// ---------------------------------------------------------------------------
// attn R13 (byte-identical; measured 106.5us): counted-vmcnt pipeline.
// kbuf[3] triple buffer, stage distance 2; V issued before stage DMA; raw
// s_barrier in main loop; __syncthreads only prologue/epilogue.
// ---------------------------------------------------------------------------
struct AttnSmem {
  union {
    __hip_bfloat16 kbuf[3][8192];   // 3 x 16 KiB triple buffer
    float ostage[256][33];          // epilogue [ch][q], pad 33
  } u;
  float redu[4][32];
  float rinv[32];
};

__global__ __launch_bounds__(256, 3) void attn_kernel(
    const __hip_bfloat16* __restrict__ qv, const __hip_bfloat16* __restrict__ kv,
    const __hip_bfloat16* __restrict__ vv,
    const float* __restrict__ x_main, const float* __restrict__ gammap,
    float* __restrict__ out)
{
  __shared__ AttnSmem sm;
  const int i  = blockIdx.x;           // 512 blocks
  const int b  = (i & 7) >> 1;         // XCD-pair -> batch (K+V L2-resident)
  const int qt = ((i >> 3) << 1) | (i & 1);
  const int n0 = qt * 32;
  const int tid  = threadIdx.x;
  const int w    = tid >> 6, lane = tid & 63, l32 = lane & 31;
  const int kh   = w >> 1, chh = w & 1;
  const int t0   = qt & 63;            // stagger: de-correlate block streams

  bf16x8 qf[8];
  {
    const __hip_bfloat16* qb = qv + ((size_t)(b * 128 + qt)) * 4096 + lane * 8;
#pragma unroll
    for (int cs = 0; cs < 8; cs++) qf[cs] = *(const bf16x8*)(qb + cs * 512);
  }

  const __hip_bfloat16* kg = kv + (size_t)(b * 128) * 4096;
  const __hip_bfloat16* vg = vv + (size_t)(b * 128) * 8192;

  auto stage = [&](int ta, int par) {
    __hip_bfloat16* kd = sm.u.kbuf[par];
    const __hip_bfloat16* ksrc = kg + (size_t)ta * 8192 + lane * 8;
#pragma unroll
    for (int c = 0; c < 4; c++) {
      int ck = w * 4 + c;
      dma16(ksrc + ck * 512, kd + ck * 512 + lane * 8);
    }
  };

  f32x16 Oacc[4];
#pragma unroll
  for (int c = 0; c < 4; c++)
#pragma unroll
    for (int r = 0; r < 16; r++) Oacc[c][r] = 0.f;

  float l_lane = 0.f;

  stage(t0, 0);
  stage((t0 + 1) & 63, 1);
  __syncthreads();                 // vmcnt(0): kbuf0/kbuf1 ready

#pragma unroll 1
  for (int lt = 0; lt < 64; ++lt) {
    const int ta = (lt + t0) & 63;

    const __hip_bfloat16* vb = vg + (size_t)(ta * 2 + kh) * 8192
                             + chh * 4096 + lane * 8;
    bf16x8 Vc[8];
#pragma unroll
    for (int c = 0; c < 4; c++) {
      Vc[2 * c]     = *(const bf16x8*)(vb + c * 1024);
      Vc[2 * c + 1] = *(const bf16x8*)(vb + c * 1024 + 512);
    }
    __builtin_amdgcn_sched_barrier(0);   // pin V-issue before DMA-issue

    if (lt < 62) stage((lt + 2 + t0) & 63, (lt + 2) % 3);

    const __hip_bfloat16* kbase = sm.u.kbuf[lt % 3] + kh * 4096 + lane * 8;
    f32x16 S = {};
#pragma unroll
    for (int cs = 0; cs < 8; cs++) {
      bf16x8 kf = *(const bf16x8*)(kbase + cs * 512);
      S = __builtin_amdgcn_mfma_f32_32x32x16_bf16(kf, qf[cs], S, 0, 0, 0);
    }

    unsigned p2[8];
    float lsub = 0.f;
#pragma unroll
    for (int i2 = 0; i2 < 8; i2++) {
      float a = exp2f(S[2 * i2]     - 64.0f);
      float c = exp2f(S[2 * i2 + 1] - 64.0f);
      lsub += a + c;
      union { __hip_bfloat162 h; unsigned u; } cv;
      cv.h = __float22bfloat162_rn(float2{a, c});
      p2[i2] = cv.u;
    }
    l_lane += lsub;
    U4 f0, f1;
    f0.u[0] = p2[0]; f0.u[1] = p2[1]; f0.u[2] = p2[2]; f0.u[3] = p2[3];
    f1.u[0] = p2[4]; f1.u[1] = p2[5]; f1.u[2] = p2[6]; f1.u[3] = p2[7];
    const bf16x8 pf0 = f0.v, pf1 = f1.v;

#pragma unroll
    for (int c = 0; c < 4; c++) {
      Oacc[c] = __builtin_amdgcn_mfma_f32_32x32x16_bf16(Vc[2 * c],     pf0, Oacc[c], 0, 0, 0);
      Oacc[c] = __builtin_amdgcn_mfma_f32_32x32x16_bf16(Vc[2 * c + 1], pf1, Oacc[c], 0, 0, 0);
    }

    if (lt < 63) {
      __builtin_amdgcn_sched_barrier(0);
      __builtin_amdgcn_s_barrier();          // raw: NO vmcnt(0) drain
      __builtin_amdgcn_sched_barrier(0);
    }
  }

  float lfull = l_lane + __shfl_xor(l_lane, 32);
  if (lane < 32) sm.redu[w][l32] = lfull;
  __syncthreads();
  const int hb = lane >> 5;
  if (kh == 0) {
#pragma unroll
    for (int c = 0; c < 4; c++) {
#pragma unroll
      for (int r = 0; r < 16; r++) {
        int ch = (chh * 4 + c) * 32 + (r & 3) + 8 * (r >> 2) + 4 * hb;
        sm.u.ostage[ch][l32] = Oacc[c][r];
      }
    }
  }
  if (tid < 32) sm.rinv[tid] = 1.0f / (sm.redu[0][tid] + sm.redu[2][tid]);
  __syncthreads();
  if (kh == 1) {
#pragma unroll
    for (int c = 0; c < 4; c++) {
#pragma unroll
      for (int r = 0; r < 16; r++) {
        int ch = (chh * 4 + c) * 32 + (r & 3) + 8 * (r >> 2) + 4 * hb;
        sm.u.ostage[ch][l32] += Oacc[c][r];
      }
    }
  }
  __syncthreads();

  const float gmm = gammap[0];
  const int pix = tid & 31;
  const float ri = sm.rinv[pix];
#pragma unroll
  for (int j = 0; j < 32; ++j) {
    int ch = (tid >> 5) * 32 + j;
    size_t g = ((size_t)(b * 256 + ch)) * 4096 + n0 + pix;
    out[g] = gmm * sm.u.ostage[ch][pix] * ri + x_main[g];
  }
}

// ---------------------------------------------------------------------------
extern "C" void kernel_launch(void* const* d_in, const int* in_sizes, int n_in,
                              void* d_out, int out_size, void* d_ws, size_t ws_size,
                              hipStream_t stream) {
  (void)in_sizes; (void)n_in; (void)out_size; (void)ws_size;
  const float* x  = (const float*)d_in[0];
  const float* z  = (const float*)d_in[1];
  const float* Wq = (const float*)d_in[2];
  const float* bq = (const float*)d_in[3];
  const float* Wk = (const float*)d_in[4];
  const float* bk = (const float*)d_in[5];
  const float* Wv = (const float*)d_in[6];
  const float* bv = (const float*)d_in[7];
  const float* gm = (const float*)d_in[8];
  float* out = (float*)d_out;

  char* ws = (char*)d_ws;
  const size_t MB = 1024 * 1024;
  __hip_bfloat16* qp  = (__hip_bfloat16*)(ws);             // 4 MiB
  __hip_bfloat16* kp  = (__hip_bfloat16*)(ws + 4 * MB);    // 4 MiB
  __hip_bfloat16* vp  = (__hip_bfloat16*)(ws + 8 * MB);    // 8 MiB
  __hip_bfloat16* wfp = (__hip_bfloat16*)(ws + 16 * MB);   // 256 KiB

  wprep_kernel<<<16, 256, 0, stream>>>(Wq, Wk, Wv, wfp);
  projfused   <<<512, 512, 0, stream>>>(x, z, wfp, bq, bk, bv, qp, kp, vp);
  attn_kernel <<<512, 256, 0, stream>>>(qp, kp, vp, x, gm, out);
}